// Round 5
// baseline (533.809 us; speedup 1.0000x reference)
//
#include <hip/hip_runtime.h>
#include <stdint.h>

#define HH 80
#define WW 80
#define CC 64
#define BB 32
#define NDIAG (HH + WW - 1)   // 159
#define SLICE (HH * WW * CC)  // 409600 f16 per (dir,b) scratch slice
#define NCW 6                 // compute waves (trapezoid stripes)
#define NIOW 3                // io waves
#define NTHREADS ((NCW + NIOW) * 64)  // 576
#define NIV 53                // 159 / 3 diagonals per barrier interval
#define PAD 72                // f16 per LDS row: 144B, 16B-aligned, 2-way banks

typedef _Float16 f16;
typedef _Float16 f16x8 __attribute__((ext_vector_type(8)));
typedef _Float16 f16x4 __attribute__((ext_vector_type(4)));
typedef float floatx4 __attribute__((ext_vector_type(4)));

struct GPtrs { const float* p[8]; };

#define WAITLGKM() do { __builtin_amdgcn_s_waitcnt(0xC07F); \
                        __builtin_amdgcn_sched_barrier(0); } while (0)

// ---------------------------------------------------------------------------
// Pre-pass: x[b][c][i][j] (f32) -> xT[((b*H+i)*W+j)*C + c] (f16), std order.
// ---------------------------------------------------------------------------
__global__ __launch_bounds__(256) void xpose_kernel(const float* __restrict__ x,
                                                    f16* __restrict__ xT) {
  const int bi = blockIdx.x;            // b*HH + i
  const int b = bi / HH, i = bi - b * HH;
  __shared__ float tile[WW][CC + 1];    // [j][c], stride 65
  const float* xp = x + ((size_t)(b * CC) * HH + i) * WW;  // + c*(H*W) + j
  for (int idx = threadIdx.x; idx < CC * WW; idx += 256) {
    const int c = idx / WW, j = idx - c * WW;   // consecutive j -> coalesced
    tile[j][c] = xp[(size_t)c * (HH * WW) + j];
  }
  __syncthreads();
  f16* op = xT + (size_t)(b * HH + i) * WW * CC;
  for (int idx = threadIdx.x; idx < (WW * CC) / 4; idx += 256) {
    const int j = idx >> 4, m = idx & 15;       // 16 lanes cover one j
    f16x4 v;
    v[0] = (f16)tile[j][m * 4 + 0];
    v[1] = (f16)tile[j][m * 4 + 1];
    v[2] = (f16)tile[j][m * 4 + 2];
    v[3] = (f16)tile[j][m * 4 + 3];
    *(f16x4*)(op + j * CC + m * 4) = v;         // 128B contiguous per 16 lanes
  }
}

// ---------------------------------------------------------------------------
// Main kernel: 128 blocks x 576 threads (6 compute + 3 io waves).
// K=3 TRAPEZOID: each barrier interval t processes diagonals D=3t, D+1, D+2.
// Compute wave wv owns shrinking windows  d0:[a0,a0+15]  d1:[a1,a1+14]
// d2:[a2,a2+13] with a1=a0+1, a2=a1+1 (clamped at the left edge), so phases
// d1/d2 read ONLY rows the wave itself just wrote -> no barrier between
// phases, just lgkmcnt(0)+sched_barrier. Stride-14 stripes x 6 waves = 84
// cells covers the widest diagonal; window overlaps recompute identical
// values (same inputs -> benign duplicate LDS writes).
// hbuf/xring are mod-6 rings: compute writes diags {D..D+2}; io flushes
// {D-3..D-1} and streams x for {D+3..D+5} (disjoint slot sets each interval).
// Compute waves are 100% vmem-free (proven necessary in rounds 2-4).
// ---------------------------------------------------------------------------
__global__ __launch_bounds__(NTHREADS, 1) void dag_kernel(const f16* __restrict__ xT,
                                                          GPtrs g,
                                                          f16* __restrict__ scratch) {
  const int blk = blockIdx.x;   // 0..127
  const int dir = blk >> 5;     // 0:SE 1:NE 2:NW 3:SW
  const int b   = blk & 31;
  const int tid = threadIdx.x;
  const int wv   = tid >> 6;    // 0..8
  const int lane = tid & 63;
  const int l15  = lane & 15;   // compute: cell-in-window (MFMA n / C-D col)
  const int quad = lane >> 4;   // compute: k-quad / C-D row-quad
  const int cq   = quad * 4;

  const bool fi      = (dir == 1) || (dir == 2);  // flip i
  const bool fj      = (dir == 2) || (dir == 3);  // flip j
  const bool do_relu = (dir != 3);                // SW scan has no ReLU
  const float* __restrict__ gv = g.p[2 * dir];
  const float* __restrict__ gh = g.p[2 * dir + 1];

  // h ring: [slot d%6][s][c]; s=i'+1, rows 0 and 81 are permanent zero guards
  // (never written: writes masked to ip<=hi -> rows<=hi+1; row d+1 of a slot
  //  is untouched since init whenever diag d is the growth edge).
  __align__(16) __shared__ f16 hbuf[6][HH + 2][PAD];   // 70,848 B
  // x ring: [slot d%6][cell][c]
  __align__(16) __shared__ f16 xring[6][HH][PAD];      // 69,120 B

  {
    f16x8 z = {};
    f16x8* hb = (f16x8*)&hbuf[0][0][0];
    for (int idx = tid; idx < (6 * (HH + 2) * PAD) / 8; idx += NTHREADS)
      hb[idx] = z;
  }

  const f16* const xTb = xT + (size_t)b * SLICE;
  f16* const sbase = scratch + (size_t)blk * SLICE;

  // global cell offset (units of CC elems) of cell index `cell` on diag dd,
  // clamped into dd's valid range (clamped duplicates are benign). io use.
  auto cellOff = [&](int dd, int cell) -> int {
    const int lo = max(0, dd - (WW - 1));
    const int hi = min(dd, HH - 1);
    const int ipc = min(max(cell, lo), hi);
    const int jp = dd - ipc;
    const int io1 = fi ? (HH - 1 - ipc) : ipc;
    const int jo1 = fj ? (WW - 1 - jp) : jp;
    return io1 * WW + jo1;
  };

  // ---- per-role persistent state (uniform scope) ----
  f16x8 Av[4][2], Ah[4][2];     // compute: gamma A-fragments
  f16x8 xb[10];                 // io: in-flight x for diags D+3..D+5
  const int cm = lane >> 3;     // io: cell-in-chunk 0..7
  const int c8 = (lane & 7) * 8;// io: channel offset

  if (wv < NCW) {
    // compute wave: load A fragments. A[m][k]: m=l15, k=quad*8+jj.
#pragma unroll
    for (int cb = 0; cb < 4; ++cb) {
      const int row = cb * 16 + l15;
      const float* pv = gv + row * CC;
      const float* ph = gh + row * CC;
#pragma unroll
      for (int jj = 0; jj < 8; ++jj) {
        Av[cb][0][jj] = (f16)pv[quad * 8 + jj];
        Av[cb][1][jj] = (f16)pv[32 + quad * 8 + jj];
        Ah[cb][0][jj] = (f16)ph[quad * 8 + jj];
        Ah[cb][1][jj] = (f16)ph[32 + quad * 8 + jj];
      }
    }
  } else {
    // io prologue: write diags 0..2 into xring, preload diags 3..5 into regs.
    const int wio = wv - NCW;   // 0..2
    f16x8 b0[10];
#pragma unroll
    for (int k = 0; k < 10; ++k) {
      const int gk = wio + 3 * k, q = gk / 10, ch = gk - q * 10;
      b0[k] = *(const f16x8*)(xTb + (cellOff(q, ch * 8 + cm) << 6) + c8);
    }
#pragma unroll
    for (int k = 0; k < 10; ++k) {
      const int gk = wio + 3 * k, q = gk / 10, ch = gk - q * 10;
      const int ipw = min(ch * 8 + cm, min(q, HH - 1));   // lo=0 for d<3
      *(f16x8*)&xring[q][ipw][c8] = b0[k];
    }
#pragma unroll
    for (int k = 0; k < 10; ++k) {
      const int gk = wio + 3 * k, q = gk / 10, ch = gk - q * 10;
      xb[k] = *(const f16x8*)(xTb + (cellOff(3 + q, ch * 8 + cm) << 6) + c8);
    }
  }

  __syncthreads();  // zero-init + x slots 0..2 visible; one-time full drain

  // one compute phase: diag with top cell index hi, window start a, width wlim
  auto cphase = [&](int hi, int a, int wlim, int rb, int wb, int xs) {
    const int ip  = a + l15;
    const int ipx = min(ip, hi);
    const int su  = min(ip, HH + 1);     // up   (i'-1,j') -> s=i'
    const int sl  = min(ip + 1, HH + 1); // left (i',j'-1) -> s=i'+1
    const f16x8 bu0 = *(const f16x8*)&hbuf[rb][su][quad * 8];
    const f16x8 bu1 = *(const f16x8*)&hbuf[rb][su][32 + quad * 8];
    const f16x8 bl0 = *(const f16x8*)&hbuf[rb][sl][quad * 8];
    const f16x8 bl1 = *(const f16x8*)&hbuf[rb][sl][32 + quad * 8];
    const bool ok = (l15 < wlim) && (ip <= hi);
    __builtin_amdgcn_s_setprio(1);
#pragma unroll
    for (int cb = 0; cb < 4; ++cb) {
      const f16x4 xv = *(const f16x4*)&xring[xs][ipx][cb * 16 + cq];
      floatx4 a1v;
      a1v[0] = (float)xv[0]; a1v[1] = (float)xv[1];   // seed C with x
      a1v[2] = (float)xv[2]; a1v[3] = (float)xv[3];
      floatx4 a2v = {0.f, 0.f, 0.f, 0.f};
      a1v = __builtin_amdgcn_mfma_f32_16x16x32_f16(Av[cb][0], bu0, a1v, 0, 0, 0);
      a2v = __builtin_amdgcn_mfma_f32_16x16x32_f16(Ah[cb][0], bl0, a2v, 0, 0, 0);
      a1v = __builtin_amdgcn_mfma_f32_16x16x32_f16(Av[cb][1], bu1, a1v, 0, 0, 0);
      a2v = __builtin_amdgcn_mfma_f32_16x16x32_f16(Ah[cb][1], bl1, a2v, 0, 0, 0);
      float h0 = a1v[0] + a2v[0], h1 = a1v[1] + a2v[1];
      float h2 = a1v[2] + a2v[2], h3 = a1v[3] + a2v[3];
      if (do_relu) {
        h0 = fmaxf(h0, 0.f); h1 = fmaxf(h1, 0.f);
        h2 = fmaxf(h2, 0.f); h3 = fmaxf(h3, 0.f);
      }
      f16x4 hw;
      hw[0] = (f16)h0; hw[1] = (f16)h1; hw[2] = (f16)h2; hw[3] = (f16)h3;
      if (ok) *(f16x4*)&hbuf[wb][ip + 1][cb * 16 + cq] = hw;
    }
    __builtin_amdgcn_s_setprio(0);
  };

  for (int t = 0; t < NIV; ++t) {
    const int D  = 3 * t;
    const int sA = (t & 1) * 3;   // slots for diags D..D+2 (D%6 = 3*(t&1))
    const int sB = 3 - sA;        // slots for D+3..D+5 (stream) / D-3..D-1 (flush)

    if (wv < NCW) {
      // ------------- compute: 3 trapezoid phases, no inner barrier ----------
      const int lo0 = max(0, D - (WW - 1)), hi0 = min(D, HH - 1);
      const int lo1 = max(0, D - (WW - 2)), hi1 = min(D + 1, HH - 1);
      const int lo2 = max(0, D - (WW - 3)), hi2 = min(D + 2, HH - 1);
      const int a2 = lo2 + 14 * wv;
      const int a1 = max(lo1, a2 - 1);
      const int a0 = max(lo0, a1 - 1);
      if (a0 <= hi0) cphase(hi0, a0, 16, sB + 2, sA + 0, sA + 0);
      WAITLGKM();                       // own d0 hbuf writes visible to self
      if (a1 <= hi1) cphase(hi1, a1, 15, sA + 0, sA + 1, sA + 1);
      WAITLGKM();                       // own d1 writes visible
      if (a2 <= hi2) cphase(hi2, a2, 14, sA + 1, sA + 2, sA + 2);
    } else {
      // ------------- io: stream x for D+3..D+5, flush h of D-3..D-1 ---------
      const int wio = wv - NCW;
      f16x8 nb[10];
#pragma unroll
      for (int k = 0; k < 10; ++k) {    // issue loads for diags D+6..D+8
        const int gk = wio + 3 * k, q = gk / 10, ch = gk - q * 10;
        const int ld = min(D + 6 + q, NDIAG - 1);
        nb[k] = *(const f16x8*)(xTb + (cellOff(ld, ch * 8 + cm) << 6) + c8);
      }
#pragma unroll
      for (int k = 0; k < 10; ++k) {    // write diags D+3..D+5 (loaded last t)
        const int gk = wio + 3 * k, q = gk / 10, ch = gk - q * 10;
        const int wd = D + 3 + q;
        const int lo = max(0, wd - (WW - 1)), hi = min(wd, HH - 1);
        const int ipw = min(max(ch * 8 + cm, lo), hi);
        *(f16x8*)&xring[sB + q][ipw][c8] = xb[k];
      }
      if (t >= 1) {
#pragma unroll
        for (int k = 0; k < 10; ++k) {  // flush diags D-3..D-1
          const int gk = wio + 3 * k, q = gk / 10, ch = gk - q * 10;
          const int cell = ch * 8 + cm;
          const int fd = D - 3 + q;
          const int lo = max(0, fd - (WW - 1)), hi = min(fd, HH - 1);
          const int ipc = min(max(cell, lo), hi);
          const f16x8 hv = *(const f16x8*)&hbuf[sB + q][ipc + 1][c8];
          *(f16x8*)(sbase + (cellOff(fd, cell) << 6) + c8) = hv;
        }
      }
#pragma unroll
      for (int k = 0; k < 10; ++k) xb[k] = nb[k];
    }

    // Raw barrier: drain LDS only (lgkmcnt(0)); vmem stays in flight.
    __builtin_amdgcn_s_waitcnt(0xC07F);  // vmcnt(63) expcnt(7) lgkmcnt(0)
    __builtin_amdgcn_s_barrier();
  }

  // final flush: diags 156..158 (156 % 6 == 0 -> slots 0,1,2)
  if (wv >= NCW) {
    const int wio = wv - NCW;
#pragma unroll
    for (int k = 0; k < 10; ++k) {
      const int gk = wio + 3 * k, q = gk / 10, ch = gk - q * 10;
      const int cell = ch * 8 + cm;
      const int fd = 156 + q;
      const int lo = max(0, fd - (WW - 1)), hi = min(fd, HH - 1);
      const int ipc = min(max(cell, lo), hi);
      const f16x8 hv = *(const f16x8*)&hbuf[q][ipc + 1][c8];
      *(f16x8*)(sbase + (cellOff(fd, cell) << 6) + c8) = hv;
    }
  }
}

// ---------------------------------------------------------------------------
// Reduce: out[b][c][i][j] = sum over 4 dirs of scratch[dir][b][i][j][c].
// ---------------------------------------------------------------------------
__global__ __launch_bounds__(256) void reduce_kernel(const f16* __restrict__ s,
                                                     float* __restrict__ out) {
  const int bi = blockIdx.x;            // b*HH + i
  const int b = bi / HH, i = bi - b * HH;
  __shared__ float tile[WW][CC + 1];    // [j][c], stride 65
  const size_t dstride = (size_t)BB * SLICE;
  const f16* p = s + (size_t)b * SLICE + (size_t)i * (WW * CC);
  for (int idx = threadIdx.x; idx < (WW * CC) / 8; idx += 256) {  // 640
    const int j = idx >> 3, c8 = (idx & 7) * 8;
    const size_t off = (size_t)j * CC + c8;
    const f16x8 a0 = *(const f16x8*)(p + off);
    const f16x8 a1 = *(const f16x8*)(p + off + dstride);
    const f16x8 a2 = *(const f16x8*)(p + off + 2 * dstride);
    const f16x8 a3 = *(const f16x8*)(p + off + 3 * dstride);
#pragma unroll
    for (int k = 0; k < 8; ++k)
      tile[j][c8 + k] = (float)a0[k] + (float)a1[k] + (float)a2[k] + (float)a3[k];
  }
  __syncthreads();
  float* op = out + ((size_t)(b * CC) * HH + i) * WW;  // + c*(H*W) + j
  const int c  = threadIdx.x >> 2;        // 0..63
  const int jb = (threadIdx.x & 3) * 4;   // 0,4,8,12
#pragma unroll
  for (int k = 0; k < 5; ++k) {
    const int j0 = jb + k * 16;
    floatx4 v;
    v[0] = tile[j0 + 0][c];
    v[1] = tile[j0 + 1][c];
    v[2] = tile[j0 + 2][c];
    v[3] = tile[j0 + 3][c];
    *(floatx4*)(op + (size_t)c * (HH * WW) + j0) = v;  // 64B per 4 lanes
  }
}

// ---------------------------------------------------------------------------
extern "C" void kernel_launch(void* const* d_in, const int* in_sizes, int n_in,
                              void* d_out, int out_size, void* d_ws, size_t ws_size,
                              hipStream_t stream) {
  const float* x = (const float*)d_in[0];
  GPtrs g;
  for (int k = 0; k < 8; ++k) g.p[k] = (const float*)d_in[k + 1];  // g1,g2,g4,g5,g7,g8,g10,g11
  f16* xT = (f16*)d_ws;                         // 26.2 MB
  f16* scratch = xT + (size_t)BB * SLICE;       // 104.9 MB

  xpose_kernel<<<BB * HH, 256, 0, stream>>>(x, xT);
  dag_kernel<<<4 * BB, NTHREADS, 0, stream>>>((const f16*)xT, g, scratch);
  reduce_kernel<<<BB * HH, 256, 0, stream>>>((const f16*)scratch, (float*)d_out);
}

// Round 7
// 266.171 us; speedup vs baseline: 2.0055x; 2.0055x over previous
//
#include <hip/hip_runtime.h>
#include <stdint.h>

#define HH 80
#define WW 80
#define CC 64
#define BB 32
#define NDIAG (HH + WW - 1)   // 159
#define SLICE (HH * WW * CC)  // 409600 f16 per (dir,b) scratch slice
#define NCW 5                 // waves; wave wv owns cells i in [16wv, 16wv+15] forever
#define NTHREADS (NCW * 64)   // 320

typedef _Float16 f16;
typedef _Float16 f16x8 __attribute__((ext_vector_type(8)));
typedef _Float16 f16x4 __attribute__((ext_vector_type(4)));
typedef float floatx4 __attribute__((ext_vector_type(4)));

struct GPtrs { const float* p[8]; };

// ---------------------------------------------------------------------------
// Channel orders.
// sigma (storage order for xT and scratch): position p = 16q + 8h + jj
//   holds channel c = 32h + 8q + jj.  A lane (q,l15)'s 16 channels are the
//   32B run [p = 16q, 16q+16) -> 2x f16x8 per cell.
// A-row permutation phi'(cb, m) = 32*(cb>>1) + 8*(m>>2) + 4*(cb&1) + (m&3):
//   loading gamma row phi'(cb, l15) for MFMA block cb makes the D layout
//   (lane (q,l15): D[cb][r] = channel 32(cb>>1)+8q+4(cb&1)+r) EQUAL to the
//   B-fragment need (lane (q,l15): B[h][jj] = channel 32h+8q+jj).  h state
//   therefore never leaves registers: B_left = own pack, B_up = DPP
//   row_shr:1 of pack (+1-cell cross-wave boundary via a 1.3KB LDS buffer).
// ROUND-7 FIX: gamma pairing was swapped in round 6.  Verified kernel pairs
//   Av(gv) with the UP neighbor and Ah(gh) with the LEFT neighbor.  Here
//   P = left (same lane, prev diag), BU = up (lane-1, prev diag), so the
//   MFMAs must be  Av*BU  and  Ah*P.
// ---------------------------------------------------------------------------

// Pre-pass: x[b][c][i][j] (f32) -> xT[((b*H+i)*W+j)*C + p] (f16, sigma order).
__global__ __launch_bounds__(256) void xpose_kernel(const float* __restrict__ x,
                                                    f16* __restrict__ xT) {
  const int bi = blockIdx.x;            // b*HH + i
  const int b = bi / HH, i = bi - b * HH;
  __shared__ float tile[WW][CC + 1];    // [j][c], stride 65
  const float* xp = x + ((size_t)(b * CC) * HH + i) * WW;  // + c*(H*W) + j
  for (int idx = threadIdx.x; idx < CC * WW; idx += 256) {
    const int c = idx / WW, j = idx - c * WW;   // consecutive j -> coalesced
    tile[j][c] = xp[(size_t)c * (HH * WW) + j];
  }
  __syncthreads();
  f16* op = xT + (size_t)(b * HH + i) * WW * CC;
  for (int idx = threadIdx.x; idx < (WW * CC) / 4; idx += 256) {
    const int j = idx >> 4, m = idx & 15;       // positions 4m..4m+3
    // p=4m+t: q=m>>2, h=(m>>1)&1, jj=4(m&1)+t -> c = 32h+8q+4(m&1)+t
    const int cbase = 32 * ((m >> 1) & 1) + 8 * (m >> 2) + 4 * (m & 1);
    f16x4 v;
    v[0] = (f16)tile[j][cbase + 0];
    v[1] = (f16)tile[j][cbase + 1];
    v[2] = (f16)tile[j][cbase + 2];
    v[3] = (f16)tile[j][cbase + 3];
    *(f16x4*)(op + j * CC + m * 4) = v;         // 128B contiguous per 16 lanes
  }
}

__device__ inline f16x8 dpp_shr1(f16x8 v) {
  union { f16x8 h; int i[4]; } s, r;
  s.h = v;
#pragma unroll
  for (int k = 0; k < 4; ++k)   // row_shr:1 (0x111): lane i <- lane i-1 in its
    r.i[k] = __builtin_amdgcn_update_dpp(0, s.i[k], 0x111, 0xF, 0xF, true);
  return r.h;                   // 16-lane row; row-start lanes get 0
}

// ---------------------------------------------------------------------------
// Main kernel: 128 blocks x 320 threads, 5 symmetric waves, h IN REGISTERS.
// Per diagonal d (159 barrier intervals):
//   BU = dpp_shr1(P) (+ boundary inject from bnd LDS for l15==0, wv>0)
//   16 MFMA: a1 = x-seed + Gv*BU (chain of 2);  a2 = Gh*P (chain of 2);
//   sum, relu, pack -> new P (zeroed outside [lo,hi]); lane l15==15 writes
//   P to bnd[d&1][wv] (2x b128); active lanes store P to scratch (2x
//   dwordx4, sigma order, 32B/lane); prefetch x for d+2 (2x f16x8, depth-2
//   double buffer XA/XB); lgkmcnt(0)-only raw barrier (vmem in flight).
// LDS = 1.3KB total; no LDS round-trip on the h critical path.
// ---------------------------------------------------------------------------
__global__ __launch_bounds__(NTHREADS, 1) void dag_kernel(const f16* __restrict__ xT,
                                                          GPtrs g,
                                                          f16* __restrict__ scratch) {
  const int blk = blockIdx.x;   // 0..127
  const int dir = blk >> 5;     // 0:SE 1:NE 2:NW 3:SW
  const int b   = blk & 31;
  const int tid = threadIdx.x;
  const int wv   = tid >> 6;    // 0..4
  const int lane = tid & 63;
  const int l15  = lane & 15;   // cell-in-window (MFMA n / D col)
  const int q    = lane >> 4;   // quad (D row-quad / B k-quad)

  const bool fi      = (dir == 1) || (dir == 2);  // flip i
  const bool fj      = (dir == 2) || (dir == 3);  // flip j
  const bool do_relu = (dir != 3);                // SW scan has no ReLU
  const float* __restrict__ gv = g.p[2 * dir];
  const float* __restrict__ gh = g.p[2 * dir + 1];

  // cross-wave boundary: pack of lane l15==15, double-buffered by diag parity
  __align__(16) __shared__ f16 bnd[2][NCW][4][16];   // 1280 B
  {
    f16x8 z = {};
    f16x8* bp = (f16x8*)&bnd[0][0][0][0];
    for (int idx = tid; idx < (2 * NCW * 4 * 16) / 8; idx += NTHREADS)
      bp[idx] = z;
  }

  const f16* const xTb = xT + (size_t)b * SLICE;
  f16* const sbase = scratch + (size_t)blk * SLICE;

  const int ip = wv * 16 + l15;            // FIXED cell row i for this lane
  const int io1 = fi ? (HH - 1 - ip) : ip; // fixed output row

  // gamma A fragments with phi' row permutation.
  f16x8 Av[4][2], Ah[4][2];
#pragma unroll
  for (int cb = 0; cb < 4; ++cb) {
    const int row = 32 * (cb >> 1) + 8 * (l15 >> 2) + 4 * (cb & 1) + (l15 & 3);
    const float* pv = gv + row * CC;
    const float* ph = gh + row * CC;
#pragma unroll
    for (int jj = 0; jj < 8; ++jj) {
      Av[cb][0][jj] = (f16)pv[q * 8 + jj];
      Av[cb][1][jj] = (f16)pv[32 + q * 8 + jj];
      Ah[cb][0][jj] = (f16)ph[q * 8 + jj];
      Ah[cb][1][jj] = (f16)ph[32 + q * 8 + jj];
    }
  }

  // x prefetch: lane's own 32B (sigma order) of its cell on diag dd.
  f16x8 XA[2], XB[2];
  auto prefetch = [&](int dd, f16x8 (&X)[2]) {
    const int lo2 = max(0, dd - (WW - 1)), hi2 = min(dd, HH - 1);
    const int ipc = min(max(ip, lo2), hi2);      // clamp: dup loads benign
    const int jp2 = dd - ipc;
    const int io2 = fi ? (HH - 1 - ipc) : ipc;
    const int jo2 = fj ? (WW - 1 - jp2) : jp2;
    const f16* xp = xTb + (((size_t)(io2 * WW + jo2)) << 6) + q * 16;
    X[0] = *(const f16x8*)(xp);      // positions 16q+0..7   (channels 8q+0..7)
    X[1] = *(const f16x8*)(xp + 8);  // positions 16q+8..15  (channels 32+8q+..)
  };
  prefetch(0, XA);
  prefetch(1, XB);

  f16x8 P0 = {}, P1 = {};    // pack of previous diag (B_left); h[-1] = 0

  __syncthreads();           // bnd zero-init visible; one-time full drain

  auto step = [&](int d, f16x8 (&X)[2], int rdp, int wrp) {
    const int lo = max(0, d - (WW - 1));
    const int hi = min(d, HH - 1);
    const bool ok = (ip >= lo) && (ip <= hi);
    // ---- B_up: shift packs down one cell; inject cross-wave boundary ----
    f16x8 BU0 = dpp_shr1(P0);
    f16x8 BU1 = dpp_shr1(P1);
    if (wv > 0) {                          // wave-uniform
      const f16x8 b0 = *(const f16x8*)&bnd[rdp][wv - 1][q][0];
      const f16x8 b1 = *(const f16x8*)&bnd[rdp][wv - 1][q][8];
      if (l15 == 0) { BU0 = b0; BU1 = b1; }
    }
    // ---- MFMA: two independent 2-deep chains per cb ----
    // FIX vs round 6: Av(gv) pairs with UP neighbor (BU); Ah(gh) with LEFT (P).
    floatx4 hs[4];
#pragma unroll
    for (int cb = 0; cb < 4; ++cb) {
      const f16x8 xs = (cb < 2) ? X[0] : X[1];
      const int eb = (cb & 1) * 4;
      floatx4 a1, a2;
      a1[0] = (float)xs[eb + 0]; a1[1] = (float)xs[eb + 1];  // seed C with x
      a1[2] = (float)xs[eb + 2]; a1[3] = (float)xs[eb + 3];
      a2[0] = 0.f; a2[1] = 0.f; a2[2] = 0.f; a2[3] = 0.f;
      a1 = __builtin_amdgcn_mfma_f32_16x16x32_f16(Av[cb][0], BU0, a1, 0, 0, 0);
      a2 = __builtin_amdgcn_mfma_f32_16x16x32_f16(Ah[cb][0], P0,  a2, 0, 0, 0);
      a1 = __builtin_amdgcn_mfma_f32_16x16x32_f16(Av[cb][1], BU1, a1, 0, 0, 0);
      a2 = __builtin_amdgcn_mfma_f32_16x16x32_f16(Ah[cb][1], P1,  a2, 0, 0, 0);
      hs[cb][0] = a1[0] + a2[0]; hs[cb][1] = a1[1] + a2[1];
      hs[cb][2] = a1[2] + a2[2]; hs[cb][3] = a1[3] + a2[3];
    }
    if (do_relu) {
#pragma unroll
      for (int cb = 0; cb < 4; ++cb)
#pragma unroll
        for (int r = 0; r < 4; ++r) hs[cb][r] = fmaxf(hs[cb][r], 0.f);
    }
    // ---- pack -> new P (D layout == next B layout); zero inactive lanes ----
    f16x8 nP0, nP1;
#pragma unroll
    for (int r = 0; r < 4; ++r) {
      nP0[r]     = (f16)hs[0][r];
      nP0[4 + r] = (f16)hs[1][r];
      nP1[r]     = (f16)hs[2][r];
      nP1[4 + r] = (f16)hs[3][r];
    }
    const f16x8 z = {};
    P0 = ok ? nP0 : z;     // inactive (esp. ip>hi) -> 0: next diag's new top
    P1 = ok ? nP1 : z;     // cell sees a zero left-neighbor
    // ---- cross-wave boundary write (lane 15 only) ----
    if (l15 == 15) {
      *(f16x8*)&bnd[wrp][wv][q][0] = P0;
      *(f16x8*)&bnd[wrp][wv][q][8] = P1;
    }
    // ---- store h to scratch (sigma order, 32B/lane, fire-and-forget) ----
    if (ok) {
      const int jp  = d - ip;
      const int jo1 = fj ? (WW - 1 - jp) : jp;
      f16* so = sbase + (((size_t)(io1 * WW + jo1)) << 6) + q * 16;
      *(f16x8*)(so)     = P0;
      *(f16x8*)(so + 8) = P1;
    }
    // ---- prefetch x for d+2 (consumed in two steps) ----
    prefetch(min(d + 2, NDIAG - 1), X);
    // ---- raw barrier: drain LDS only; vmem stays in flight ----
    __builtin_amdgcn_s_waitcnt(0xC07F);  // vmcnt(63) expcnt(7) lgkmcnt(0)
    __builtin_amdgcn_s_barrier();
  };

  for (int d = 0; d < NDIAG - 1; d += 2) {  // parity literals -> folded indices
    step(d,     XA, 1, 0);
    step(d + 1, XB, 0, 1);
  }
  step(NDIAG - 1, XA, 1, 0);  // 158 is even
}

// ---------------------------------------------------------------------------
// Reduce: out[b][c][i][j] = sum over 4 dirs of scratch[dir][b][i][j][p],
// un-permuting sigma: position group k (8 f16) holds channels
// c0 = 32*(k&1) + 8*(k>>1) .. c0+7 (contiguous).
// ---------------------------------------------------------------------------
__global__ __launch_bounds__(256) void reduce_kernel(const f16* __restrict__ s,
                                                     float* __restrict__ out) {
  const int bi = blockIdx.x;            // b*HH + i
  const int b = bi / HH, i = bi - b * HH;
  __shared__ float tile[WW][CC + 1];    // [j][c], stride 65
  const size_t dstride = (size_t)BB * SLICE;
  const f16* p = s + (size_t)b * SLICE + (size_t)i * (WW * CC);
  for (int idx = threadIdx.x; idx < (WW * CC) / 8; idx += 256) {  // 640
    const int j = idx >> 3, k = idx & 7;
    const size_t off = (size_t)j * CC + k * 8;
    const f16x8 a0 = *(const f16x8*)(p + off);
    const f16x8 a1 = *(const f16x8*)(p + off + dstride);
    const f16x8 a2 = *(const f16x8*)(p + off + 2 * dstride);
    const f16x8 a3 = *(const f16x8*)(p + off + 3 * dstride);
    const int c0 = 32 * (k & 1) + 8 * (k >> 1);
#pragma unroll
    for (int t = 0; t < 8; ++t)
      tile[j][c0 + t] = (float)a0[t] + (float)a1[t] + (float)a2[t] + (float)a3[t];
  }
  __syncthreads();
  float* op = out + ((size_t)(b * CC) * HH + i) * WW;  // + c*(H*W) + j
  const int c  = threadIdx.x >> 2;        // 0..63
  const int jb = (threadIdx.x & 3) * 4;   // 0,4,8,12
#pragma unroll
  for (int k = 0; k < 5; ++k) {
    const int j0 = jb + k * 16;
    floatx4 v;
    v[0] = tile[j0 + 0][c];
    v[1] = tile[j0 + 1][c];
    v[2] = tile[j0 + 2][c];
    v[3] = tile[j0 + 3][c];
    *(floatx4*)(op + (size_t)c * (HH * WW) + j0) = v;  // 64B per 4 lanes
  }
}

// ---------------------------------------------------------------------------
extern "C" void kernel_launch(void* const* d_in, const int* in_sizes, int n_in,
                              void* d_out, int out_size, void* d_ws, size_t ws_size,
                              hipStream_t stream) {
  const float* x = (const float*)d_in[0];
  GPtrs g;
  for (int k = 0; k < 8; ++k) g.p[k] = (const float*)d_in[k + 1];  // g1,g2,g4,g5,g7,g8,g10,g11
  f16* xT = (f16*)d_ws;                         // 26.2 MB
  f16* scratch = xT + (size_t)BB * SLICE;       // 104.9 MB

  xpose_kernel<<<BB * HH, 256, 0, stream>>>(x, xT);
  dag_kernel<<<4 * BB, NTHREADS, 0, stream>>>((const f16*)xT, g, scratch);
  reduce_kernel<<<BB * HH, 256, 0, stream>>>((const f16*)scratch, (float*)d_out);
}

// Round 8
// 225.412 us; speedup vs baseline: 2.3681x; 1.1808x over previous
//
#include <hip/hip_runtime.h>
#include <stdint.h>

#define HH 80
#define WW 80
#define CC 64
#define BB 32
#define NDIAG (HH + WW - 1)   // 159
#define SLICE (HH * WW * CC)  // 409600 f16 per (dir,b) scratch slice
#define NCW 5                 // waves; wave wv owns cells i in [16wv, 16wv+15]
#define NTHREADS (NCW * 64)   // 320
#define RINGD 8               // bnd ring depth (diagonals)

typedef _Float16 f16;
typedef _Float16 f16x8 __attribute__((ext_vector_type(8)));
typedef _Float16 f16x4 __attribute__((ext_vector_type(4)));
typedef float floatx4 __attribute__((ext_vector_type(4)));

struct GPtrs { const float* p[8]; };

// ---------------------------------------------------------------------------
// Layouts identical to the PASSING round-7 kernel:
// sigma storage order (xT, scratch): position p = 16q + 8h + jj holds channel
//   c = 32h + 8q + jj (lane (q,l15) owns one 32B run per cell).
// A-row permutation phi'(cb,m) = 32*(cb>>1) + 8*(m>>2) + 4*(cb&1) + (m&3)
//   makes MFMA D layout == next-diag B layout (h never leaves registers).
// Pairing (R7-verified): Av(gv) x BU(up neighbor), Ah(gh) x P(left neighbor).
// ROUND-8 CHANGE: no s_barrier. Waves free-run; the only cross-wave dep
// (wv-1 lane15 -> wv lane0, lag 1 diag) goes through a depth-8 bnd ring with
// per-wave LDS progress flags (acyclic wait graph -> deadlock-free).
// ---------------------------------------------------------------------------

// Pre-pass: x[b][c][i][j] (f32) -> xT[((b*H+i)*W+j)*C + p] (f16, sigma order).
__global__ __launch_bounds__(256) void xpose_kernel(const float* __restrict__ x,
                                                    f16* __restrict__ xT) {
  const int bi = blockIdx.x;            // b*HH + i
  const int b = bi / HH, i = bi - b * HH;
  __shared__ float tile[WW][CC + 1];    // [j][c], stride 65
  const float* xp = x + ((size_t)(b * CC) * HH + i) * WW;  // + c*(H*W) + j
  for (int idx = threadIdx.x; idx < CC * WW; idx += 256) {
    const int c = idx / WW, j = idx - c * WW;   // consecutive j -> coalesced
    tile[j][c] = xp[(size_t)c * (HH * WW) + j];
  }
  __syncthreads();
  f16* op = xT + (size_t)(b * HH + i) * WW * CC;
  for (int idx = threadIdx.x; idx < (WW * CC) / 4; idx += 256) {
    const int j = idx >> 4, m = idx & 15;       // positions 4m..4m+3
    const int cbase = 32 * ((m >> 1) & 1) + 8 * (m >> 2) + 4 * (m & 1);
    f16x4 v;
    v[0] = (f16)tile[j][cbase + 0];
    v[1] = (f16)tile[j][cbase + 1];
    v[2] = (f16)tile[j][cbase + 2];
    v[3] = (f16)tile[j][cbase + 3];
    *(f16x4*)(op + j * CC + m * 4) = v;         // 128B contiguous per 16 lanes
  }
}

__device__ inline f16x8 dpp_shr1(f16x8 v) {
  union { f16x8 h; int i[4]; } s, r;
  s.h = v;
#pragma unroll
  for (int k = 0; k < 4; ++k)   // row_shr:1: lane i <- lane i-1 within 16-rows
    r.i[k] = __builtin_amdgcn_update_dpp(0, s.i[k], 0x111, 0xF, 0xF, true);
  return r.h;                   // row-start lanes get 0
}

// ---------------------------------------------------------------------------
// Main kernel: 128 blocks x 320 threads, 5 FREE-RUNNING waves, h in registers.
// Wave wv runs its own 96-step loop over diags d = 16wv + k (k in [0,95];
// k=95 is inert padding for the unroll). Per step:
//   early: a2 = x-seed + Gh*P (left nbr; own regs, no sync needed)
//   poll flags[wv-1] >= d-1 (cached) -> read bnd ring -> inject lane0's BU
//   late:  a1 = Gv*BU (up nbr); sum, relu, pack -> new P (D==B layout)
//   throttle flags[wv+1] >= d-7 -> lane15 writes bnd[d&7]
//   lgkmcnt(0); lane0 releases flags[wv] = d (relaxed LDS atomic; manual
//     fence avoids the vmcnt(0) a workgroup-release would emit)
//   store h to scratch (parity-staged regs, fire-and-forget); prefetch x
//     for d+4 (depth-4 ring X0..X3 covers cold-HBM latency)
// No s_barrier anywhere in the loop: total time ~= 159 x per-wave chain.
// ---------------------------------------------------------------------------
__global__ __launch_bounds__(NTHREADS, 1) void dag_kernel(const f16* __restrict__ xT,
                                                          GPtrs g,
                                                          f16* __restrict__ scratch) {
  const int blk = blockIdx.x;   // 0..127
  const int dir = blk >> 5;     // 0:SE 1:NE 2:NW 3:SW
  const int b   = blk & 31;
  const int tid = threadIdx.x;
  const int wv   = tid >> 6;    // 0..4
  const int lane = tid & 63;
  const int l15  = lane & 15;   // cell-in-window (MFMA n / D col)
  const int q    = lane >> 4;   // quad (D row-quad / B k-quad)

  const bool fi      = (dir == 1) || (dir == 2);  // flip i
  const bool fj      = (dir == 2) || (dir == 3);  // flip j
  const bool do_relu = (dir != 3);                // SW scan has no ReLU
  const float* __restrict__ gv = g.p[2 * dir];
  const float* __restrict__ gh = g.p[2 * dir + 1];

  // bnd ring: slot d&7 holds wave wv's lane-15 pack of diag d. 5120 B.
  __align__(16) __shared__ f16 bnd[RINGD][NCW][4][16];
  __shared__ int flags[NCW];    // last completed diag per wave
  if (tid < NCW) flags[tid] = 16 * tid - 1;   // "completed start-1"

  const f16* const xTb = xT + (size_t)b * SLICE;
  f16* const sbase = scratch + (size_t)blk * SLICE;

  const int ip    = wv * 16 + l15;           // FIXED cell row i for this lane
  const int io1   = fi ? (HH - 1 - ip) : ip; // fixed output row
  const int dbase = wv * 16;                 // wave's first active diagonal

  // gamma A fragments with phi' row permutation (verified R7).
  f16x8 Av[4][2], Ah[4][2];
#pragma unroll
  for (int cb = 0; cb < 4; ++cb) {
    const int row = 32 * (cb >> 1) + 8 * (l15 >> 2) + 4 * (cb & 1) + (l15 & 3);
    const float* pv = gv + row * CC;
    const float* ph = gh + row * CC;
#pragma unroll
    for (int jj = 0; jj < 8; ++jj) {
      Av[cb][0][jj] = (f16)pv[q * 8 + jj];
      Av[cb][1][jj] = (f16)pv[32 + q * 8 + jj];
      Ah[cb][0][jj] = (f16)ph[q * 8 + jj];
      Ah[cb][1][jj] = (f16)ph[32 + q * 8 + jj];
    }
  }

  // x prefetch: lane's own 32B (sigma order) of its cell on diag dd.
  auto prefetch = [&](int dd, f16x8 (&X)[2]) {
    const int lo2 = max(0, dd - (WW - 1)), hi2 = min(dd, HH - 1);
    const int ipc = min(max(ip, lo2), hi2);      // clamp: dup loads benign
    const int jp2 = dd - ipc;
    const int io2 = fi ? (HH - 1 - ipc) : ipc;
    const int jo2 = fj ? (WW - 1 - jp2) : jp2;
    const f16* xp = xTb + (((size_t)(io2 * WW + jo2)) << 6) + q * 16;
    X[0] = *(const f16x8*)(xp);
    X[1] = *(const f16x8*)(xp + 8);
  };

  f16x8 X0[2], X1[2], X2[2], X3[2];            // depth-4 prefetch ring
  prefetch(dbase + 0, X0);
  prefetch(dbase + 1, X1);
  prefetch(dbase + 2, X2);
  prefetch(dbase + 3, X3);

  f16x8 P0 = {}, P1 = {};      // h pack of previous diag; h[-1] = 0
  f16x8 SE0, SE1, SO0, SO1;    // store staging (parity -> 2-step slack)
  int fup = -0x40000000;       // cached upstream flag
  int fdn = -0x40000000;       // cached downstream flag

  __syncthreads();             // flags init visible; the ONLY barrier

  auto step = [&](int k, f16x8 (&X)[2], f16x8& S0, f16x8& S1) {
    const int d  = dbase + k;
    const int lo = max(0, d - (WW - 1));
    const int hi = min(d, HH - 1);
    const bool ok = (ip >= lo) && (ip <= hi);

    // B_up from own registers (pre-poll, register-only)
    f16x8 BU0 = dpp_shr1(P0);
    f16x8 BU1 = dpp_shr1(P1);

    // early chains: a2 = x-seed + Gh * P(left) — independent of neighbor
    floatx4 hs[4];
#pragma unroll
    for (int cb = 0; cb < 4; ++cb) {
      const f16x8 xs = (cb < 2) ? X[0] : X[1];
      const int eb = (cb & 1) * 4;
      floatx4 a2;
      a2[0] = (float)xs[eb + 0]; a2[1] = (float)xs[eb + 1];
      a2[2] = (float)xs[eb + 2]; a2[3] = (float)xs[eb + 3];
      a2 = __builtin_amdgcn_mfma_f32_16x16x32_f16(Ah[cb][0], P0, a2, 0, 0, 0);
      a2 = __builtin_amdgcn_mfma_f32_16x16x32_f16(Ah[cb][1], P1, a2, 0, 0, 0);
      hs[cb] = a2;
    }

    // upstream poll (cached) + boundary inject; lane0 active iff k <= 79
    if (wv > 0 && k <= 79) {
      if (fup < d - 1) {
        do {
          fup = __hip_atomic_load(&flags[wv - 1], __ATOMIC_RELAXED,
                                  __HIP_MEMORY_SCOPE_WORKGROUP);
        } while (fup < d - 1);
      }
      __builtin_amdgcn_sched_barrier(0);   // keep bnd reads after the poll
      const f16x8 b0 = *(const f16x8*)&bnd[(d - 1) & (RINGD - 1)][wv - 1][q][0];
      const f16x8 b1 = *(const f16x8*)&bnd[(d - 1) & (RINGD - 1)][wv - 1][q][8];
      if (l15 == 0) { BU0 = b0; BU1 = b1; }
    }

    // late chains: a1 = Gv * BU(up)
#pragma unroll
    for (int cb = 0; cb < 4; ++cb) {
      floatx4 a1 = {0.f, 0.f, 0.f, 0.f};
      a1 = __builtin_amdgcn_mfma_f32_16x16x32_f16(Av[cb][0], BU0, a1, 0, 0, 0);
      a1 = __builtin_amdgcn_mfma_f32_16x16x32_f16(Av[cb][1], BU1, a1, 0, 0, 0);
      hs[cb][0] += a1[0]; hs[cb][1] += a1[1];
      hs[cb][2] += a1[2]; hs[cb][3] += a1[3];
    }
    if (do_relu) {
#pragma unroll
      for (int cb = 0; cb < 4; ++cb)
#pragma unroll
        for (int r = 0; r < 4; ++r) hs[cb][r] = fmaxf(hs[cb][r], 0.f);
    }
    // pack -> new P (D layout == next B layout); zero inactive lanes
    f16x8 nP0, nP1;
#pragma unroll
    for (int r = 0; r < 4; ++r) {
      nP0[r]     = (f16)hs[0][r];
      nP0[4 + r] = (f16)hs[1][r];
      nP1[r]     = (f16)hs[2][r];
      nP1[4 + r] = (f16)hs[3][r];
    }
    const f16x8 z = {};
    P0 = ok ? nP0 : z;
    P1 = ok ? nP1 : z;

    // downstream throttle + bnd ring write (lane15 active iff 15<=k<=94)
    if (wv < NCW - 1 && k >= 15 && k <= 94) {
      if (fdn < d - (RINGD - 1)) {
        do {
          fdn = __hip_atomic_load(&flags[wv + 1], __ATOMIC_RELAXED,
                                  __HIP_MEMORY_SCOPE_WORKGROUP);
        } while (fdn < d - (RINGD - 1));
      }
      __builtin_amdgcn_sched_barrier(0);   // keep bnd write after the throttle
      if (l15 == 15) {
        *(f16x8*)&bnd[d & (RINGD - 1)][wv][q][0] = P0;
        *(f16x8*)&bnd[d & (RINGD - 1)][wv][q][8] = P1;
      }
    }
    // release: drain LDS (bnd write) then publish progress. Manual fence =
    // lgkmcnt(0) only — a workgroup-release atomic would also drain vmcnt.
    __builtin_amdgcn_s_waitcnt(0xC07F);    // vmcnt(63) expcnt(7) lgkmcnt(0)
    __builtin_amdgcn_sched_barrier(0);
    if (lane == 0)
      __hip_atomic_store(&flags[wv], d, __ATOMIC_RELAXED,
                         __HIP_MEMORY_SCOPE_WORKGROUP);

    // store h to scratch (staged regs -> 2-step slack on store-data hazard)
    if (ok) {
      S0 = P0; S1 = P1;
      const int jp  = d - ip;
      const int jo1 = fj ? (WW - 1 - jp) : jp;
      f16* so = sbase + (((size_t)(io1 * WW + jo1)) << 6) + q * 16;
      *(f16x8*)(so)     = S0;
      *(f16x8*)(so + 8) = S1;
    }
    // prefetch x for d+4 into this step's slot
    prefetch(min(d + 4, NDIAG - 1), X);
  };

  for (int k = 0; k < 96; k += 4) {   // k=95 step is inert (all lanes ok=false)
    step(k,     X0, SE0, SE1);
    step(k + 1, X1, SO0, SO1);
    step(k + 2, X2, SE0, SE1);
    step(k + 3, X3, SO0, SO1);
  }
}

// ---------------------------------------------------------------------------
// Reduce: out[b][c][i][j] = sum over 4 dirs of scratch[dir][b][i][j][p],
// un-permuting sigma: group k holds channels c0 = 32*(k&1) + 8*(k>>1) .. +7.
// ---------------------------------------------------------------------------
__global__ __launch_bounds__(256) void reduce_kernel(const f16* __restrict__ s,
                                                     float* __restrict__ out) {
  const int bi = blockIdx.x;            // b*HH + i
  const int b = bi / HH, i = bi - b * HH;
  __shared__ float tile[WW][CC + 1];    // [j][c], stride 65
  const size_t dstride = (size_t)BB * SLICE;
  const f16* p = s + (size_t)b * SLICE + (size_t)i * (WW * CC);
  for (int idx = threadIdx.x; idx < (WW * CC) / 8; idx += 256) {  // 640
    const int j = idx >> 3, k = idx & 7;
    const size_t off = (size_t)j * CC + k * 8;
    const f16x8 a0 = *(const f16x8*)(p + off);
    const f16x8 a1 = *(const f16x8*)(p + off + dstride);
    const f16x8 a2 = *(const f16x8*)(p + off + 2 * dstride);
    const f16x8 a3 = *(const f16x8*)(p + off + 3 * dstride);
    const int c0 = 32 * (k & 1) + 8 * (k >> 1);
#pragma unroll
    for (int t = 0; t < 8; ++t)
      tile[j][c0 + t] = (float)a0[t] + (float)a1[t] + (float)a2[t] + (float)a3[t];
  }
  __syncthreads();
  float* op = out + ((size_t)(b * CC) * HH + i) * WW;  // + c*(H*W) + j
  const int c  = threadIdx.x >> 2;        // 0..63
  const int jb = (threadIdx.x & 3) * 4;   // 0,4,8,12
#pragma unroll
  for (int k = 0; k < 5; ++k) {
    const int j0 = jb + k * 16;
    floatx4 v;
    v[0] = tile[j0 + 0][c];
    v[1] = tile[j0 + 1][c];
    v[2] = tile[j0 + 2][c];
    v[3] = tile[j0 + 3][c];
    *(floatx4*)(op + (size_t)c * (HH * WW) + j0) = v;  // 64B per 4 lanes
  }
}

// ---------------------------------------------------------------------------
extern "C" void kernel_launch(void* const* d_in, const int* in_sizes, int n_in,
                              void* d_out, int out_size, void* d_ws, size_t ws_size,
                              hipStream_t stream) {
  const float* x = (const float*)d_in[0];
  GPtrs g;
  for (int k = 0; k < 8; ++k) g.p[k] = (const float*)d_in[k + 1];  // g1,g2,g4,g5,g7,g8,g10,g11
  f16* xT = (f16*)d_ws;                         // 26.2 MB
  f16* scratch = xT + (size_t)BB * SLICE;       // 104.9 MB

  xpose_kernel<<<BB * HH, 256, 0, stream>>>(x, xT);
  dag_kernel<<<4 * BB, NTHREADS, 0, stream>>>((const f16*)xT, g, scratch);
  reduce_kernel<<<BB * HH, 256, 0, stream>>>((const f16*)scratch, (float*)d_out);
}